// Round 3
// baseline (272.065 us; speedup 1.0000x reference)
//
#include <hip/hip_runtime.h>
#include <math.h>

#define BN 8
#define CN 64
#define HN 256
#define WN 256
#define HWN (HN * WN)          // 65536
#define NPIX (BN * HWN)        // 524288 pixels (b,h,w)
#define NTOT (BN * CN * HWN)   // 33554432 elements

#define TILE 32                // output tile (TILE x TILE)
#define GPAD 3                 // halo: 2 (5x5 DoG) + 1 (3x3 Sobel)
#define GDIM (TILE + 2 * GPAD) // 38
#define GLDS 40                // padded LDS row stride (gray)
#define DDIM (TILE + 2)        // 34
#define DLDS 36                // padded LDS row stride (dog)
#define CS 2                   // channel splits per tile (occupancy boost)

struct DogK { float k[25]; };  // gk1 - gk2, 5x5 row-major

// K1: gray = mean_c x. float2 per thread -> 1024 blocks -> 16 waves/CU.
__global__ __launch_bounds__(256) void gray_kernel(const float* __restrict__ x,
                                                   float* __restrict__ gray) {
    int idx = blockIdx.x * blockDim.x + threadIdx.x;   // float2-pixel index
    if (idx >= NPIX / 2) return;
    int p2 = idx * 2;
    int b  = p2 / HWN;
    int hw = p2 - b * HWN;
    const float2* xp = (const float2*)(x + (size_t)b * CN * HWN + hw);
    int cs = blockIdx.x & (CN - 1);   // decorrelate channel order across blocks
    float2 acc = make_float2(0.f, 0.f);
    #pragma unroll 8
    for (int i = 0; i < CN; ++i) {
        int c = (i + cs) & (CN - 1);
        float2 v = xp[c * (HWN / 2)];
        acc.x += v.x; acc.y += v.y;
    }
    const float s = 1.0f / (float)CN;
    *(float2*)(gray + p2) = make_float2(acc.x * s, acc.y * s);
}

// K2: fused DoG -> Sobel -> mag -> sigmoid -> out = x*(1+att).
// Each tile handled by CS blocks; each applies CN/CS channels.
__global__ __launch_bounds__(256) void fused_kernel(const float* __restrict__ x,
                                                    const float* __restrict__ gray,
                                                    float* __restrict__ out,
                                                    const float* __restrict__ gwp,
                                                    const float* __restrict__ gbp,
                                                    DogK dk) {
    __shared__ float sGray[GDIM * GLDS];
    __shared__ float sDog[DDIM * DLDS];

    int bid = blockIdx.x;
    int b   = bid >> 7;                   // 64 tiles * CS(2) = 128 blocks per image
    int rem = bid & 127;
    int t   = rem >> 1;                   // tile id 0..63
    int csp = rem & 1;                    // channel split 0..CS-1
    int th0 = (t >> 3) * TILE;
    int tw0 = (t & 7) * TILE;
    int tid = threadIdx.x;

    const float* g = gray + b * HWN;

    // Stage gray tile (38x38), zero outside image.
    for (int i = tid; i < GDIM * GDIM; i += 256) {
        int r = i / GDIM, c = i - r * GDIM;
        int gh = th0 - GPAD + r;
        int gw = tw0 - GPAD + c;
        float v = 0.f;
        if (gh >= 0 && gh < HN && gw >= 0 && gw < WN) v = g[gh * WN + gw];
        sGray[r * GLDS + c] = v;
    }
    __syncthreads();

    // DoG on 34x34; out-of-image positions forced to 0 (Sobel zero-pads the
    // dog ARRAY, not a composed conv).
    for (int i = tid; i < DDIM * DDIM; i += 256) {
        int r = i / DDIM, c = i - r * DDIM;
        int gh = th0 - 1 + r;
        int gw = tw0 - 1 + c;
        float v = 0.f;
        if (gh >= 0 && gh < HN && gw >= 0 && gw < WN) {
            float acc = 0.f;
            #pragma unroll
            for (int di = 0; di < 5; ++di)
                #pragma unroll
                for (int dj = 0; dj < 5; ++dj)
                    acc += dk.k[di * 5 + dj] * sGray[(r + di) * GLDS + (c + dj)];
            v = acc;
        }
        sDog[r * DLDS + c] = v;
    }
    __syncthreads();

    // Per-thread: one float4 of pixels. Sobel + mag + gate.
    int h  = tid >> 3;
    int w4 = (tid & 7) * 4;
    float gwv = gwp[0], gbv = gbp[0];
    float a[4];
    #pragma unroll
    for (int k = 0; k < 4; ++k) {
        int r = h + 1, c = w4 + k + 1;
        float d00 = sDog[(r - 1) * DLDS + (c - 1)];
        float d01 = sDog[(r - 1) * DLDS + (c    )];
        float d02 = sDog[(r - 1) * DLDS + (c + 1)];
        float d10 = sDog[(r    ) * DLDS + (c - 1)];
        float d12 = sDog[(r    ) * DLDS + (c + 1)];
        float d20 = sDog[(r + 1) * DLDS + (c - 1)];
        float d21 = sDog[(r + 1) * DLDS + (c    )];
        float d22 = sDog[(r + 1) * DLDS + (c + 1)];
        float gx = (d02 - d00) + 2.f * (d12 - d10) + (d22 - d20);
        float gy = (d20 - d00) + 2.f * (d21 - d01) + (d22 - d02);
        float mag = sqrtf(gx * gx + gy * gy + 1e-6f);
        float z = mag * gwv + gbv;
        a[k] = 1.f + 1.f / (1.f + expf(-z));
    }
    float4 av = make_float4(a[0], a[1], a[2], a[3]);

    // Apply CN/CS channels: out = x * (1+att). float4, coalesced.
    int c0 = csp * (CN / CS);
    size_t base = ((size_t)b * CN + c0) * HWN + (size_t)(th0 + h) * WN + (tw0 + w4);
    const float* xb = x + base;
    float* ob = out + base;
    #pragma unroll 4
    for (int c = 0; c < CN / CS; ++c) {
        float4 xv = *(const float4*)(xb + (size_t)c * HWN);
        float4 o  = make_float4(xv.x * av.x, xv.y * av.y, xv.z * av.z, xv.w * av.w);
        *(float4*)(ob + (size_t)c * HWN) = o;
    }
}

extern "C" void kernel_launch(void* const* d_in, const int* in_sizes, int n_in,
                              void* d_out, int out_size, void* d_ws, size_t ws_size,
                              hipStream_t stream) {
    const float* x  = (const float*)d_in[0];
    const float* gw = (const float*)d_in[1];
    const float* gb = (const float*)d_in[2];
    float* out  = (float*)d_out;
    float* gray = (float*)d_ws;   // NPIX floats = 2 MB

    // Host-side DoG taps (pure CPU math; graph-capture safe).
    DogK dk;
    {
        double k1[25], k2[25], s1 = 0.0, s2 = 0.0;
        for (int i = 0; i < 5; ++i) {
            for (int j = 0; j < 5; ++j) {
                double di = i - 2.0, dj = j - 2.0;
                double r2 = di * di + dj * dj;
                k1[i * 5 + j] = exp(-r2 / (2.0 * 1.0 * 1.0));
                k2[i * 5 + j] = exp(-r2 / (2.0 * 2.0 * 2.0));
                s1 += k1[i * 5 + j];
                s2 += k2[i * 5 + j];
            }
        }
        for (int t = 0; t < 25; ++t)
            dk.k[t] = (float)(k1[t] / s1 - k2[t] / s2);
    }

    gray_kernel <<<dim3(NPIX / 2 / 256),  dim3(256), 0, stream>>>(x, gray);
    fused_kernel<<<dim3(BN * 64 * CS),    dim3(256), 0, stream>>>(x, gray, out, gw, gb, dk);
}